// Round 4
// baseline (3748.735 us; speedup 1.0000x reference)
//
#include <hip/hip_runtime.h>
#include <hip/hip_bf16.h>

typedef __attribute__((ext_vector_type(4))) float f32x4;
typedef __attribute__((ext_vector_type(8))) short s16x8;
typedef __attribute__((ext_vector_type(4))) short s16x4;

constexpr int Bc = 4, Sc = 1024, Dc = 1024, Hc = 16, DHc = 64, Lc = 12, Vc = 32000;
constexpr int Tc = Bc * Sc;   // 4096 tokens
constexpr int D3c = 3 * Dc;   // 3072

static __device__ __forceinline__ short f2bf(float f) {
  union { float f; unsigned u; } v; v.f = f;
  unsigned r = (v.u + 0x7FFFu + ((v.u >> 16) & 1u)) >> 16;   // RNE
  return (short)r;
}

// ---------------- embedding + positional (pe indexed by BATCH per reference) ----
__launch_bounds__(256)
__global__ void k_embed(const int* __restrict__ X, const float* __restrict__ emb,
                        const float* __restrict__ pe, float* __restrict__ x) {
  int row = blockIdx.x;            // 0..4095 = b*S + s
  int b = row >> 10;               // S = 1024
  int tok = X[row];
  int t = threadIdx.x;             // 256 threads, D/4 float4 each
  float4 e = ((const float4*)(emb + (size_t)tok * Dc))[t];
  float4 p = ((const float4*)(pe + (size_t)b * Dc))[t];
  float4 r;
  r.x = e.x * 32.0f + p.x;  r.y = e.y * 32.0f + p.y;
  r.z = e.z * 32.0f + p.z;  r.w = e.w * 32.0f + p.w;
  ((float4*)(x + (size_t)row * Dc))[t] = r;
}

// ---------------- layernorm: fp32 stats, writes optional fp32 + bf16 ----------
template<bool WF32>
__launch_bounds__(256)
__global__ void k_ln(const float* __restrict__ x, const float* __restrict__ g,
                     const float* __restrict__ be, float* __restrict__ hf,
                     short* __restrict__ hb) {
  int row = blockIdx.x, t = threadIdx.x;
  float4 v = ((const float4*)(x + (size_t)row * Dc))[t];
  float s1 = v.x + v.y + v.z + v.w;
  float s2 = v.x * v.x + v.y * v.y + v.z * v.z + v.w * v.w;
#pragma unroll
  for (int off = 1; off < 64; off <<= 1) {
    s1 += __shfl_xor(s1, off);
    s2 += __shfl_xor(s2, off);
  }
  __shared__ float a1[4], a2[4];
  if ((t & 63) == 0) { a1[t >> 6] = s1; a2[t >> 6] = s2; }
  __syncthreads();
  s1 = a1[0] + a1[1] + a1[2] + a1[3];
  s2 = a2[0] + a2[1] + a2[2] + a2[3];
  float mu = s1 * (1.0f / Dc);
  float var = s2 * (1.0f / Dc) - mu * mu;
  float rs = rsqrtf(var + 1e-5f);
  float4 gg = ((const float4*)g)[t];
  float4 bb = ((const float4*)be)[t];
  float4 r;
  r.x = (v.x - mu) * rs * gg.x + bb.x;
  r.y = (v.y - mu) * rs * gg.y + bb.y;
  r.z = (v.z - mu) * rs * gg.z + bb.z;
  r.w = (v.w - mu) * rs * gg.w + bb.w;
  if (WF32) ((float4*)(hf + (size_t)row * Dc))[t] = r;
  s16x4 o; o[0] = f2bf(r.x); o[1] = f2bf(r.y); o[2] = f2bf(r.z); o[3] = f2bf(r.w);
  ((s16x4*)(hb + (size_t)row * Dc))[t] = o;
}

// ---------------- fp32 [R][C] -> bf16 [C][R] transpose (per-layer via z) ------
__launch_bounds__(256)
__global__ void k_transpose_bf(const float* __restrict__ in0, short* __restrict__ out0,
                               int R, int C) {
  const float* in = in0 + (size_t)blockIdx.z * R * C;
  short* out = out0 + (size_t)blockIdx.z * R * C;
  __shared__ float tile[64][65];
  int c0 = blockIdx.x * 64, r0 = blockIdx.y * 64;
  int t = threadIdx.x;
#pragma unroll
  for (int e = 0; e < 16; ++e) {
    int idx = e * 256 + t;
    int r = idx >> 6, c = idx & 63;
    tile[r][c] = in[(size_t)(r0 + r) * C + c0 + c];
  }
  __syncthreads();
#pragma unroll
  for (int e = 0; e < 16; ++e) {
    int idx = e * 256 + t;
    int c = idx >> 6, r = idx & 63;
    out[(size_t)(c0 + c) * R + r0 + r] = f2bf(tile[r][c]);
  }
}

// ---------------- fp32 -> bf16 elementwise ------------------------------------
__launch_bounds__(256)
__global__ void k_f2bf(const float* __restrict__ in, short* __restrict__ out, size_t n) {
  size_t i = ((size_t)blockIdx.x * 256 + threadIdx.x) * 4;
  size_t stride = (size_t)gridDim.x * 1024;
  for (; i < n; i += stride) {
    float4 v = *(const float4*)(in + i);
    s16x4 r; r[0] = f2bf(v.x); r[1] = f2bf(v.y); r[2] = f2bf(v.z); r[3] = f2bf(v.w);
    *(s16x4*)(out + i) = r;
  }
}

// ---------------- bf16 MFMA GEMM (m97 structure): C = A[M,K] @ Bt[N,K]^T ------
// 128x128 tile, BK=64, global_load_lds dwordx4 staging, XOR-swizzled LDS
// (linear dest + inverse-swizzled global source + same involution on ds_read).
// SWZ 0: by = bid % nby (M-fast).
// SWZ 2: logits mapping — XCD k (bid&7) owns M-blocks [4k,4k+4) x all N-panels,
//        N outer: A-slice (1 MB) stays resident in that XCD's L2, B streams once.
// MODE 0: bf16 out, +bias (QKV); MODE 1: f32 out, +bias +residual; MODE 2: f32 plain.
template<int MODE, int SWZ>
__launch_bounds__(256)
__global__ void k_gemm(const short* __restrict__ A, const short* __restrict__ Bt,
                       const float* __restrict__ bias, const float* __restrict__ res,
                       void* __restrict__ Cout, int M, int N, int K, int nby) {
  __shared__ __align__(16) short Al[128][64];
  __shared__ __align__(16) short Bl[128][64];
  int bid = blockIdx.x;
  int by, bx;
  if (SWZ == 2) {
    int xcd = bid & 7, i = bid >> 3;   // grid == 8000, i in [0,1000)
    by = xcd * 4 + (i & 3);            // 4 M-blocks per XCD
    bx = i >> 2;                       // N outer
  } else {
    by = bid % nby;
    bx = bid / nby;
  }
  int m0 = by * 128, n0 = bx * 128;
  int t = threadIdx.x;
  int w = t >> 6, lane = t & 63;
  int wr = w >> 1, wc = w & 1;               // 2x2 wave grid, 64x64 per wave
  int lg = lane >> 4, lr = lane & 15;

  int srow = t >> 3, sg = t & 7;
  int scol = ((sg ^ (srow & 7)) * 8);
  const short* ga = A + (size_t)(m0 + srow) * K + scol;
  const short* gb = Bt + (size_t)(n0 + srow) * K + scol;
  short* la = &Al[srow][sg * 8];
  short* lb = &Bl[srow][sg * 8];

  f32x4 acc[4][4];
#pragma unroll
  for (int i = 0; i < 4; ++i)
#pragma unroll
    for (int j = 0; j < 4; ++j) { acc[i][j][0] = 0.f; acc[i][j][1] = 0.f; acc[i][j][2] = 0.f; acc[i][j][3] = 0.f; }

  for (int k0 = 0; k0 < K; k0 += 64) {
#pragma unroll
    for (int i = 0; i < 4; ++i) {
      __builtin_amdgcn_global_load_lds(
          (const __attribute__((address_space(1))) void*)(ga + (size_t)(i * 32) * K + k0),
          (__attribute__((address_space(3))) void*)(la + i * 32 * 64), 16, 0, 0);
      __builtin_amdgcn_global_load_lds(
          (const __attribute__((address_space(1))) void*)(gb + (size_t)(i * 32) * K + k0),
          (__attribute__((address_space(3))) void*)(lb + i * 32 * 64), 16, 0, 0);
    }
    __syncthreads();
#pragma unroll
    for (int kk = 0; kk < 2; ++kk) {
      s16x8 af[4], bfr[4];
#pragma unroll
      for (int mi = 0; mi < 4; ++mi) {
        int row = wr * 64 + mi * 16 + lr;
        af[mi] = *(const s16x8*)&Al[row][((kk * 4 + lg) ^ (lr & 7)) * 8];
      }
#pragma unroll
      for (int ni = 0; ni < 4; ++ni) {
        int row = wc * 64 + ni * 16 + lr;
        bfr[ni] = *(const s16x8*)&Bl[row][((kk * 4 + lg) ^ (lr & 7)) * 8];
      }
#pragma unroll
      for (int mi = 0; mi < 4; ++mi)
#pragma unroll
        for (int ni = 0; ni < 4; ++ni)
          acc[mi][ni] = __builtin_amdgcn_mfma_f32_16x16x32_bf16(af[mi], bfr[ni], acc[mi][ni], 0, 0, 0);
    }
    __syncthreads();
  }
  // epilogue — C/D layout: col = lane&15, row = (lane>>4)*4 + reg  [m89-verified]
#pragma unroll
  for (int mi = 0; mi < 4; ++mi) {
#pragma unroll
    for (int ni = 0; ni < 4; ++ni) {
      int ncol = n0 + wc * 64 + ni * 16 + lr;
      float bv = (MODE == 2) ? 0.0f : bias[ncol];
      int mbase = m0 + wr * 64 + mi * 16 + lg * 4;
#pragma unroll
      for (int j = 0; j < 4; ++j) {
        size_t idx = (size_t)(mbase + j) * N + ncol;
        float vv = acc[mi][ni][j] + bv;
        if (MODE == 1) vv += res[idx];
        if (MODE == 0) ((short*)Cout)[idx] = f2bf(vv);
        else           ((float*)Cout)[idx] = vv;
      }
    }
  }
}

// ---------------- fused flash attention, swapped-operand form -----------------
// No 1/sqrt(d) scaling (per reference); exp-direct softmax (scores small).
// S^T = mfma(K_frag, Q_frag): Q regs serve as B-fragment unchanged; C-layout
// gives each lane 4 CONSECUTIVE k per f-block -> vectorized P writes (b64).
// PV: O^T = mfma(V^T_frag, P_frag); output packs 4 consecutive dh -> 8B stores.
// V staged via register transpose: 4x8B loads -> 4x b64 LDS writes (<=2-way).
__launch_bounds__(256)
__global__ void k_attn(const short* __restrict__ qkv, short* __restrict__ obf) {
  int bh = blockIdx.x;
  int b = bh >> 4, h = bh & 15;
  int q0 = blockIdx.y * 64;
  int t = threadIdx.x, w = t >> 6, lane = t & 63;
  int lg = lane >> 4, lr = lane & 15;
  __shared__ __align__(16) short vls[64][72];   // V^T [dh][sk]
  __shared__ __align__(16) short pls[64][72];   // P   [q_local][k]
  s16x8 qf0, qf1;
  {
    const short* qp = qkv + (size_t)(b * Sc + q0 + w * 16 + lr) * D3c + h * DHc + lg * 8;
    qf0 = *(const s16x8*)qp;
    qf1 = *(const s16x8*)(qp + 32);
  }
  float lsum = 0.0f;
  f32x4 oacc[4];
#pragma unroll
  for (int f = 0; f < 4; ++f) { oacc[f][0] = 0.f; oacc[f][1] = 0.f; oacc[f][2] = 0.f; oacc[f][3] = 0.f; }

  int va = t & 15;                 // sk quad: sk0 = va*4
  int vb = t >> 4;                 // dh quad: dh0 = vb*4
  const short* vbase = qkv + (size_t)(b * Sc) * D3c + 2 * Dc + h * DHc + vb * 4;
  const short* kbase = qkv + (size_t)(b * Sc) * D3c + Dc + h * DHc;

  for (int kt = 0; kt < Sc / 64; ++kt) {
    int k0 = kt * 64;
    __syncthreads();                       // PV(kt-1) readers done: vls/pls free
    {
      // register-transpose V: [sk][dh] -> vls[dh][sk]
      s16x4 ld0 = *(const s16x4*)(vbase + (size_t)(k0 + va * 4 + 0) * D3c);
      s16x4 ld1 = *(const s16x4*)(vbase + (size_t)(k0 + va * 4 + 1) * D3c);
      s16x4 ld2 = *(const s16x4*)(vbase + (size_t)(k0 + va * 4 + 2) * D3c);
      s16x4 ld3 = *(const s16x4*)(vbase + (size_t)(k0 + va * 4 + 3) * D3c);
#pragma unroll
      for (int e = 0; e < 4; ++e) {
        s16x4 pk; pk[0] = ld0[e]; pk[1] = ld1[e]; pk[2] = ld2[e]; pk[3] = ld3[e];
        *(s16x4*)&vls[vb * 4 + e][va * 4] = pk;
      }
    }
    // S^T[k][q] per f-block: lane holds k = f*16+lg*4+j, q = w*16+lr
#pragma unroll
    for (int f = 0; f < 4; ++f) {
      const short* kp = kbase + (size_t)(k0 + f * 16 + lr) * D3c + lg * 8;
      s16x8 kf0 = *(const s16x8*)kp;
      s16x8 kf1 = *(const s16x8*)(kp + 32);
      f32x4 c; c[0] = 0.f; c[1] = 0.f; c[2] = 0.f; c[3] = 0.f;
      c = __builtin_amdgcn_mfma_f32_16x16x32_bf16(kf0, qf0, c, 0, 0, 0);
      c = __builtin_amdgcn_mfma_f32_16x16x32_bf16(kf1, qf1, c, 0, 0, 0);
      float p0 = __expf(c[0]), p1 = __expf(c[1]), p2 = __expf(c[2]), p3 = __expf(c[3]);
      lsum += (p0 + p1) + (p2 + p3);
      s16x4 pk; pk[0] = f2bf(p0); pk[1] = f2bf(p1); pk[2] = f2bf(p2); pk[3] = f2bf(p3);
      *(s16x4*)&pls[w * 16 + lr][f * 16 + lg * 4] = pk;
    }
    __syncthreads();                       // V and P staged
    s16x8 pb0 = *(const s16x8*)&pls[w * 16 + lr][lg * 8];
    s16x8 pb1 = *(const s16x8*)&pls[w * 16 + lr][32 + lg * 8];
#pragma unroll
    for (int f = 0; f < 4; ++f) {
      s16x8 af0 = *(const s16x8*)&vls[f * 16 + lr][lg * 8];
      s16x8 af1 = *(const s16x8*)&vls[f * 16 + lr][32 + lg * 8];
      oacc[f] = __builtin_amdgcn_mfma_f32_16x16x32_bf16(af0, pb0, oacc[f], 0, 0, 0);
      oacc[f] = __builtin_amdgcn_mfma_f32_16x16x32_bf16(af1, pb1, oacc[f], 0, 0, 0);
    }
  }
  // row-sum: lane owns q = w*16+lr; partials spread across the 4 lane-groups
  lsum += __shfl_xor(lsum, 16);
  lsum += __shfl_xor(lsum, 32);
  float inv = 1.0f / lsum;
  int qrow = q0 + w * 16 + lr;
#pragma unroll
  for (int f = 0; f < 4; ++f) {
    s16x4 ok;
#pragma unroll
    for (int j = 0; j < 4; ++j) ok[j] = f2bf(oacc[f][j] * inv);
    *(s16x4*)(obf + (size_t)(b * Sc + qrow) * Dc + h * DHc + f * 16 + lg * 4) = ok;
  }
}

// ---------------- orchestration ----------------------------------------------
extern "C" void kernel_launch(void* const* d_in, const int* in_sizes, int n_in,
                              void* d_out, int out_size, void* d_ws, size_t ws_size,
                              hipStream_t stream) {
  const int*   X    = (const int*)d_in[0];
  const float* emb  = (const float*)d_in[1];
  const float* pe   = (const float*)d_in[2];
  const float* ln1g = (const float*)d_in[3];
  const float* ln1b = (const float*)d_in[4];
  const float* wa   = (const float*)d_in[5];
  const float* ba   = (const float*)d_in[6];
  const float* wp   = (const float*)d_in[7];
  const float* bp   = (const float*)d_in[8];
  const float* ln2g = (const float*)d_in[9];
  const float* ln2b = (const float*)d_in[10];
  const float* wf   = (const float*)d_in[11];
  const float* bfv  = (const float*)d_in[12];
  const float* wout = (const float*)d_in[13];
  float* out = (float*)d_out;

  char* p = (char*)d_ws;
  float* x    = (float*)p; p += (size_t)Tc * Dc * 4;
  float* hx   = (float*)p; p += (size_t)Tc * Dc * 4;
  short* hbf  = (short*)p; p += (size_t)Tc * Dc * 2;
  short* l2bf = (short*)p; p += (size_t)Tc * Dc * 2;
  short* qkvb = (short*)p; p += (size_t)Tc * D3c * 2;
  short* obf  = (short*)p; p += (size_t)Tc * Dc * 2;
  short* xbf  = (short*)p; p += (size_t)Tc * Dc * 2;
  short* wat  = (short*)p; p += (size_t)Lc * D3c * Dc * 2;
  short* wpt  = (short*)p; p += (size_t)Lc * Dc * Dc * 2;
  short* wft  = (short*)p; p += (size_t)Lc * Dc * Dc * 2;
  short* woutb = (short*)p; p += (size_t)Vc * Dc * 2;
  // total ws use ≈ 284 MB

  // weight prep (runs every call; ws is re-poisoned by harness)
  k_transpose_bf<<<dim3(D3c / 64, Dc / 64, Lc), 256, 0, stream>>>(wa, wat, Dc, D3c);
  k_transpose_bf<<<dim3(Dc / 64, Dc / 64, Lc), 256, 0, stream>>>(wp, wpt, Dc, Dc);
  k_transpose_bf<<<dim3(Dc / 64, Dc / 64, Lc), 256, 0, stream>>>(wf, wft, Dc, Dc);
  k_f2bf<<<4096, 256, 0, stream>>>(wout, woutb, (size_t)Vc * Dc);

  k_embed<<<Tc, 256, 0, stream>>>(X, emb, pe, x);

  const int nby = Tc / 128;   // 32 M-blocks
  for (int l = 0; l < Lc; ++l) {
    k_ln<true><<<Tc, 256, 0, stream>>>(x, ln1g + l * Dc, ln1b + l * Dc, hx, hbf);
    k_gemm<0, 0><<<(D3c / 128) * nby, 256, 0, stream>>>(
        hbf, wat + (size_t)l * D3c * Dc, ba + l * D3c, nullptr, qkvb, Tc, D3c, Dc, nby);
    k_attn<<<dim3(Bc * Hc, Sc / 64), 256, 0, stream>>>(qkvb, obf);
    k_gemm<1, 0><<<(Dc / 128) * nby, 256, 0, stream>>>(
        obf, wpt + (size_t)l * Dc * Dc, bp + l * Dc, hx, x, Tc, Dc, Dc, nby);
    k_ln<false><<<Tc, 256, 0, stream>>>(x, ln2g + l * Dc, ln2b + l * Dc, nullptr, l2bf);
    k_gemm<1, 0><<<(Dc / 128) * nby, 256, 0, stream>>>(
        l2bf, wft + (size_t)l * Dc * Dc, bfv + l * Dc, x, x, Tc, Dc, Dc, nby);
  }

  k_f2bf<<<2048, 256, 0, stream>>>(x, xbf, (size_t)Tc * Dc);
  k_gemm<2, 2><<<(Vc / 128) * nby, 256, 0, stream>>>(
      xbf, woutb, nullptr, nullptr, out, Tc, Vc, Dc, nby);
}